// Round 5
// baseline (93.432 us; speedup 1.0000x reference)
//
#include <hip/hip_runtime.h>
#include <math.h>

#define NG 1024  // max gaussians (N is 1024 in this problem)
#define TS 8     // pixel tile size (8x8 = 64 px = one wave)

// ws float offsets (sorted AoS arrays + count)
#define BBB_OFF  (15*NG)     // float4[NG]: (umin, vmin, umax, vmax) sorted
#define BD0_OFF  (19*NG)     // float4[NG]: (u, v, A2, B)            sorted
#define BD1_OFF  (23*NG)     // float4[NG]: (C2, op, r, g)           sorted
#define BD2_OFF  (27*NG)     // float [NG]: b                        sorted
#define WS_CNT_OFF (28*NG)

// Fused: per-gaussian wave computes its depth-rank (lane-parallel over j,
// recomputing zc/keep inline from raw inputs), then does the projection /
// conic / SH math wave-uniformly and scatters straight to its sorted slot.
// No inter-block dependency: rank needs only raw means/opac.
__global__ __launch_bounds__(256) void prep_rank_kernel(
    const float* __restrict__ means, const float* __restrict__ scales,
    const float* __restrict__ quats, const float* __restrict__ fdc,
    const float* __restrict__ frest, const float* __restrict__ opac,
    const float* __restrict__ vm, const float* __restrict__ Km,
    float* __restrict__ ws, int N)
{
    int tid = threadIdx.x;
    int lane = tid & 63;
    int i = blockIdx.x * 4 + (tid >> 6);
    if (i >= N) return;

    float r00 = vm[0], r01 = vm[1], r02 = vm[2],  t0 = vm[3];
    float r10 = vm[4], r11 = vm[5], r12 = vm[6],  t1 = vm[7];
    float r20 = vm[8], r21 = vm[9], r22 = vm[10], t2 = vm[11];
    float fx = Km[0], cx = Km[2], fy = Km[4], cy = Km[5];

    // own z/keep — pinned __fmaf_rn chain so the j-loop recompute is
    // bitwise identical (rank permutation must be bijective)
    float mx = means[3*i+0], my = means[3*i+1], mz = means[3*i+2];
    float pzi = __fmaf_rn(r20, mx, __fmaf_rn(r21, my, __fmaf_rn(r22, mz, t2)));
    float opsi = 1.f / (1.f + __expf(-opac[i]));
    bool ki = (pzi > 0.01f) && (opsi >= (1.f/255.f));
    // (det>0 clause of the reference is provably always true here:
    //  det = a*c-b^2 with a=a'+0.3, c=c'+0.3, b^2 <= a'c' (PSD) => det >= 0.09)

    int r = 0, cnt = 0;
    for (int j = lane; j < N; j += 64) {
        float jx = means[3*j+0], jy = means[3*j+1], jz = means[3*j+2];
        float pzj = __fmaf_rn(r20, jx, __fmaf_rn(r21, jy, __fmaf_rn(r22, jz, t2)));
        float opsj = 1.f / (1.f + __expf(-opac[j]));
        bool kj = (pzj > 0.01f) && (opsj >= (1.f/255.f));
        if (kj) {
            cnt++;
            if (pzj < pzi || (pzj == pzi && j < i)) r++;   // j==i: both false
        }
    }
    int packed = r | (cnt << 16);
    #pragma unroll
    for (int s = 32; s; s >>= 1) packed += __shfl_xor(packed, s);
    r = packed & 0xffff;
    cnt = (int)((unsigned)packed >> 16);

    if (i == 0 && lane == 0) ((int*)(ws + WS_CNT_OFF))[0] = cnt;
    if (!ki) return;

    // ---- projection / conic / SH (wave-uniform redundant compute) ----
    float px = r00*mx + r01*my + r02*mz + t0;
    float py = r10*mx + r11*my + r12*mz + t1;
    float zc = fmaxf(pzi, 0.01f);

    float qw = quats[4*i+0], qx = quats[4*i+1], qy = quats[4*i+2], qz = quats[4*i+3];
    float qn = rsqrtf(qw*qw + qx*qx + qy*qy + qz*qz);
    qw *= qn; qx *= qn; qy *= qn; qz *= qn;
    float R00 = 1.f - 2.f*(qy*qy + qz*qz), R01 = 2.f*(qx*qy - qw*qz), R02 = 2.f*(qx*qz + qw*qy);
    float R10 = 2.f*(qx*qy + qw*qz), R11 = 1.f - 2.f*(qx*qx + qz*qz), R12 = 2.f*(qy*qz - qw*qx);
    float R20 = 2.f*(qx*qz - qw*qy), R21 = 2.f*(qy*qz + qw*qx), R22 = 1.f - 2.f*(qx*qx + qy*qy);

    float s0 = __expf(scales[3*i+0]), s1 = __expf(scales[3*i+1]), s2 = __expf(scales[3*i+2]);
    float M00 = R00*s0, M01 = R01*s1, M02 = R02*s2;
    float M10 = R10*s0, M11 = R11*s1, M12 = R12*s2;
    float M20 = R20*s0, M21 = R21*s1, M22 = R22*s2;
    float c00 = M00*M00 + M01*M01 + M02*M02;
    float c01 = M00*M10 + M01*M11 + M02*M12;
    float c02 = M00*M20 + M01*M21 + M02*M22;
    float c11 = M10*M10 + M11*M11 + M12*M12;
    float c12 = M10*M20 + M11*M21 + M12*M22;
    float c22 = M20*M20 + M21*M21 + M22*M22;
    float P00 = r00*c00 + r01*c01 + r02*c02;
    float P01 = r00*c01 + r01*c11 + r02*c12;
    float P02 = r00*c02 + r01*c12 + r02*c22;
    float P10 = r10*c00 + r11*c01 + r12*c02;
    float P11 = r10*c01 + r11*c11 + r12*c12;
    float P12 = r10*c02 + r11*c12 + r12*c22;
    float P20 = r20*c00 + r21*c01 + r22*c02;
    float P21 = r20*c01 + r21*c11 + r22*c12;
    float P22 = r20*c02 + r21*c12 + r22*c22;
    float w00 = P00*r00 + P01*r01 + P02*r02;
    float w01 = P00*r10 + P01*r11 + P02*r12;
    float w02 = P00*r20 + P01*r21 + P02*r22;
    float w11 = P10*r10 + P11*r11 + P12*r12;
    float w12 = P10*r20 + P11*r21 + P12*r22;
    float w22 = P20*r20 + P21*r21 + P22*r22;

    float g0 = fx / zc;
    float g2 = -fx * px / (zc * zc);
    float h1 = fy / zc;
    float h2 = -fy * py / (zc * zc);
    float a = g0*g0*w00 + 2.f*g0*g2*w02 + g2*g2*w22 + 0.3f;
    float b = g0*(w01*h1 + w02*h2) + g2*(w12*h1 + w22*h2);
    float c = h1*h1*w11 + 2.f*h1*h2*w12 + h2*h2*w22 + 0.3f;
    float det = a*c - b*b;
    float det_safe = (det > 0.f) ? det : 1.f;
    float conicA = c / det_safe;
    float conicB = -b / det_safe;
    float conicC = a / det_safe;

    float u = fx * px / zc + cx;
    float v = fy * py / zc + cy;

    // SH deg3
    float cpx = -(r00*t0 + r10*t1 + r20*t2);
    float cpy = -(r01*t0 + r11*t1 + r21*t2);
    float cpz = -(r02*t0 + r12*t1 + r22*t2);
    float vx = mx - cpx, vy = my - cpy, vz = mz - cpz;
    float vn = rsqrtf(vx*vx + vy*vy + vz*vz);
    float x = vx*vn, y = vy*vn, z = vz*vn;
    float xx = x*x, yy = y*y, zz = z*z;
    float bs[16];
    bs[0]  = 0.28209479177387814f;
    bs[1]  = -0.4886025119029199f * y;
    bs[2]  = 0.4886025119029199f * z;
    bs[3]  = -0.4886025119029199f * x;
    bs[4]  = 1.0925484305920792f * x * y;
    bs[5]  = -1.0925484305920792f * y * z;
    bs[6]  = 0.31539156525252005f * (2.f*zz - xx - yy);
    bs[7]  = -1.0925484305920792f * x * z;
    bs[8]  = 0.5462742152960396f * (xx - yy);
    bs[9]  = -0.5900435899266435f * y * (3.f*xx - yy);
    bs[10] = 2.890611442640554f * x * y * z;
    bs[11] = -0.4570457994644658f * y * (4.f*zz - xx - yy);
    bs[12] = 0.37317633259011546f * z * (2.f*zz - 3.f*xx - 3.f*yy);
    bs[13] = -0.4570457994644658f * x * (4.f*zz - xx - yy);
    bs[14] = 1.445305721320277f * z * (xx - yy);
    bs[15] = -0.5900435899266435f * x * (xx - 3.f*yy);

    float cr = bs[0]*fdc[3*i+0];
    float cg = bs[0]*fdc[3*i+1];
    float cb = bs[0]*fdc[3*i+2];
    #pragma unroll
    for (int k = 1; k < 16; ++k) {
        const float* f = frest + (i*15 + (k-1))*3;
        cr += bs[k]*f[0];
        cg += bs[k]*f[1];
        cb += bs[k]*f[2];
    }
    cr = fmaxf(cr + 0.5f, 0.f);
    cg = fmaxf(cg + 0.5f, 0.f);
    cb = fmaxf(cb + 0.5f, 0.f);

    // conservative alpha>=1/255 footprint (bbox); exact w.r.t. per-pixel test
    float tau = fmaxf(__logf(255.f * opsi), 0.f);
    float rx = 1.01f * sqrtf(2.f * tau * a) + 1.0f;
    float ry = 1.01f * sqrtf(2.f * tau * c) + 1.0f;

    if (lane == 0) {
        ((float4*)(ws + BBB_OFF))[r] = make_float4(u - rx, v - ry, u + rx, v + ry);
        ((float4*)(ws + BD0_OFF))[r] = make_float4(u, v, 0.5f*conicA, conicB);
        ((float4*)(ws + BD1_OFF))[r] = make_float4(0.5f*conicC, opsi, cr, cg);
        (ws + BD2_OFF)[r] = cb;
    }
}

// one 8x8 pixel tile per 64-thread block; batch-ballot cull over sorted list
__global__ __launch_bounds__(64) void composite_tile(
    const float* __restrict__ ws, const float* __restrict__ bg,
    float* __restrict__ out, int W, int H, int ntx)
{
    __shared__ float4 ds0[64], ds1[64];
    __shared__ float  ds2[64];
    const int M = *(const int*)(ws + WS_CNT_OFF);
    const float4* bbB = (const float4*)(ws + BBB_OFF);
    const float4* d0B = (const float4*)(ws + BD0_OFF);
    const float4* d1B = (const float4*)(ws + BD1_OFF);
    const float*  d2B = ws + BD2_OFF;

    int lane = threadIdx.x;
    int tx = blockIdx.x % ntx, ty = blockIdx.x / ntx;
    float tx0 = tx*TS + 0.5f, tx1 = tx*TS + (TS - 0.5f);
    float ty0 = ty*TS + 0.5f, ty1 = ty*TS + (TS - 0.5f);
    int px = tx*TS + (lane & (TS-1)), py = ty*TS + (lane >> 3);
    float gx = px + 0.5f, gy = py + 0.5f;

    float T = 1.f, cr = 0.f, cg = 0.f, cb = 0.f;

    float4 cbb = make_float4(1e30f, 1e30f, -1e30f, -1e30f);
    float4 c0 = make_float4(0,0,0,0), c1 = make_float4(0,0,0,0);
    float  c2 = 0.f;
    if (lane < M) { cbb = bbB[lane]; c0 = d0B[lane]; c1 = d1B[lane]; c2 = d2B[lane]; }

    for (int base = 0; base < M; base += 64) {
        // prefetch next batch while we work on this one
        int nj = base + 64 + lane;
        float4 nbb = make_float4(1e30f, 1e30f, -1e30f, -1e30f);
        float4 n0 = make_float4(0,0,0,0), n1 = make_float4(0,0,0,0);
        float  n2 = 0.f;
        if (nj < M) { nbb = bbB[nj]; n0 = d0B[nj]; n1 = d1B[nj]; n2 = d2B[nj]; }

        bool ov = (base + lane < M) &
                  (cbb.x <= tx1) & (cbb.z >= tx0) &
                  (cbb.y <= ty1) & (cbb.w >= ty0);
        unsigned long long m = __ballot(ov);
        if (m) {
            ds0[lane] = c0; ds1[lane] = c1; ds2[lane] = c2;
            while (m) {
                int j = (int)__builtin_ctzll(m);
                m &= m - 1;
                float4 q0 = ds0[j];       // u, v, A2, B
                float4 q1 = ds1[j];       // C2, op, r, g
                float bc = ds2[j];
                float dx = gx - q0.x, dy = gy - q0.y;
                float sg = fmaf(dx, fmaf(q0.z, dx, q0.w*dy), q1.x*(dy*dy));
                float e  = __expf(-sg);
                float al = fminf(q1.y * e, 0.999f);
                bool ok = (sg >= 0.f) & (al >= 0.00392156862745098f);
                al = ok ? al : 0.f;
                float w = T * al;
                cr = fmaf(w, q1.z, cr);
                cg = fmaf(w, q1.w, cg);
                cb = fmaf(w, bc, cb);
                T = fmaf(-al, T, T);
            }
        }
        cbb = nbb; c0 = n0; c1 = n1; c2 = n2;
    }

    if (px < W && py < H) {
        int p = py*W + px;
        out[3*p+0] = fmaf(T, bg[0], cr);
        out[3*p+1] = fmaf(T, bg[1], cg);
        out[3*p+2] = fmaf(T, bg[2], cb);
    }
}

extern "C" void kernel_launch(void* const* d_in, const int* in_sizes, int n_in,
                              void* d_out, int out_size, void* d_ws, size_t ws_size,
                              hipStream_t stream) {
    const float* means  = (const float*)d_in[0];
    const float* scales = (const float*)d_in[1];
    const float* quats  = (const float*)d_in[2];
    const float* fdc    = (const float*)d_in[3];
    const float* frest  = (const float*)d_in[4];
    const float* opac   = (const float*)d_in[5];
    const float* vm     = (const float*)d_in[6];
    const float* Km     = (const float*)d_in[7];
    const float* bg     = (const float*)d_in[8];

    int N  = in_sizes[0] / 3;     // 1024
    int HW = out_size / 3;        // H*W
    // recover W,H host-side (square in this problem; divisor fallback otherwise)
    int W = (int)(sqrtf((float)HW) + 0.5f);
    while (W > 1 && HW % W) --W;
    int H = HW / W;

    float* ws  = (float*)d_ws;
    float* out = (float*)d_out;

    prep_rank_kernel<<<(N + 3) / 4, 256, 0, stream>>>(means, scales, quats, fdc,
                                                      frest, opac, vm, Km, ws, N);

    int ntx = (W + TS - 1) / TS;
    int nty = (H + TS - 1) / TS;
    composite_tile<<<ntx * nty, 64, 0, stream>>>(ws, bg, out, W, H, ntx);
}

// Round 7
// 89.599 us; speedup vs baseline: 1.0428x; 1.0428x over previous
//
#include <hip/hip_runtime.h>
#include <math.h>

#define NG 1024  // max gaussians (N is 1024 in this problem)
#define TS 8     // pixel tile size (8x8 = 64 px = one wave)

// ws float offsets (sorted AoS arrays + count)
#define BBB_OFF  (15*NG)     // float4[NG]: (umin, vmin, umax, vmax) sorted
#define BD0_OFF  (19*NG)     // float4[NG]: (u, v, A2, B)            sorted
#define BD1_OFF  (23*NG)     // float4[NG]: (C2, op, r, g)           sorted
#define BD2_OFF  (27*NG)     // float [NG]: b                        sorted
#define WS_CNT_OFF (28*NG)

// Fused prep+rank. Per block: stage all (pz, keep) into LDS (coalesced,
// computed identically in every block -> bitwise-identical ranks), then one
// wave per gaussian does the lane-parallel rank over LDS, the wave-uniform
// projection/conic/SH math, and lane 0 scatters to the sorted slot.
__global__ __launch_bounds__(256) void prep_rank_kernel(
    const float* __restrict__ means, const float* __restrict__ scales,
    const float* __restrict__ quats, const float* __restrict__ fdc,
    const float* __restrict__ frest, const float* __restrict__ opac,
    const float* __restrict__ vm, const float* __restrict__ Km,
    float* __restrict__ ws, int N)
{
    __shared__ float2 zk[NG];
    int tid = threadIdx.x;

    float r00 = vm[0], r01 = vm[1], r02 = vm[2],  t0 = vm[3];
    float r10 = vm[4], r11 = vm[5], r12 = vm[6],  t1 = vm[7];
    float r20 = vm[8], r21 = vm[9], r22 = vm[10], t2 = vm[11];
    float fx = Km[0], cx = Km[2], fy = Km[4], cy = Km[5];

    // stage (pz, keep) for all gaussians — pinned __fmaf_rn chain, identical
    // in every block (determinism requirement for the rank permutation)
    for (int j = tid; j < N; j += 256) {
        float jx = means[3*j+0], jy = means[3*j+1], jz = means[3*j+2];
        float pz = __fmaf_rn(r20, jx, __fmaf_rn(r21, jy, __fmaf_rn(r22, jz, t2)));
        float ops = 1.f / (1.f + __expf(-opac[j]));
        bool k = (pz > 0.01f) && (ops >= (1.f/255.f));
        // (reference's det>0 clause is provably always true: det >= 0.09)
        zk[j] = make_float2(pz, k ? 1.f : 0.f);
    }
    __syncthreads();

    int lane = tid & 63;
    int i = blockIdx.x * 4 + (tid >> 6);
    if (i >= N) return;

    float2 me = zk[i];
    float pzi = me.x;
    bool ki = me.y != 0.f;

    int r = 0, cnt = 0;
    for (int j = lane; j < N; j += 64) {
        float2 vj = zk[j];
        if (vj.y != 0.f) {
            cnt++;
            if (vj.x < pzi || (vj.x == pzi && j < i)) r++;   // j==i: both false
        }
    }
    int packed = r | (cnt << 16);
    #pragma unroll
    for (int s = 32; s; s >>= 1) packed += __shfl_xor(packed, s);
    r = packed & 0xffff;
    cnt = (int)((unsigned)packed >> 16);

    if (i == 0 && lane == 0) ((int*)(ws + WS_CNT_OFF))[0] = cnt;
    if (!ki) return;

    // ---- projection / conic / SH (wave-uniform redundant compute) ----
    float mx = means[3*i+0], my = means[3*i+1], mz = means[3*i+2];
    float px = r00*mx + r01*my + r02*mz + t0;
    float py = r10*mx + r11*my + r12*mz + t1;
    float zc = fmaxf(pzi, 0.01f);
    float opsi = 1.f / (1.f + __expf(-opac[i]));

    float qw = quats[4*i+0], qx = quats[4*i+1], qy = quats[4*i+2], qz = quats[4*i+3];
    float qn = rsqrtf(qw*qw + qx*qx + qy*qy + qz*qz);
    qw *= qn; qx *= qn; qy *= qn; qz *= qn;
    float R00 = 1.f - 2.f*(qy*qy + qz*qz), R01 = 2.f*(qx*qy - qw*qz), R02 = 2.f*(qx*qz + qw*qy);
    float R10 = 2.f*(qx*qy + qw*qz), R11 = 1.f - 2.f*(qx*qx + qz*qz), R12 = 2.f*(qy*qz - qw*qx);
    float R20 = 2.f*(qx*qz - qw*qy), R21 = 2.f*(qy*qz + qw*qx), R22 = 1.f - 2.f*(qx*qx + qy*qy);

    float s0 = __expf(scales[3*i+0]), s1 = __expf(scales[3*i+1]), s2 = __expf(scales[3*i+2]);
    float M00 = R00*s0, M01 = R01*s1, M02 = R02*s2;
    float M10 = R10*s0, M11 = R11*s1, M12 = R12*s2;
    float M20 = R20*s0, M21 = R21*s1, M22 = R22*s2;
    float c00 = M00*M00 + M01*M01 + M02*M02;
    float c01 = M00*M10 + M01*M11 + M02*M12;
    float c02 = M00*M20 + M01*M21 + M02*M22;
    float c11 = M10*M10 + M11*M11 + M12*M12;
    float c12 = M10*M20 + M11*M21 + M12*M22;
    float c22 = M20*M20 + M21*M21 + M22*M22;
    float P00 = r00*c00 + r01*c01 + r02*c02;
    float P01 = r00*c01 + r01*c11 + r02*c12;
    float P02 = r00*c02 + r01*c12 + r02*c22;
    float P10 = r10*c00 + r11*c01 + r12*c02;
    float P11 = r10*c01 + r11*c11 + r12*c12;
    float P12 = r10*c02 + r11*c12 + r12*c22;
    float P20 = r20*c00 + r21*c01 + r22*c02;
    float P21 = r20*c01 + r21*c11 + r22*c12;
    float P22 = r20*c02 + r21*c12 + r22*c22;
    float w00 = P00*r00 + P01*r01 + P02*r02;
    float w01 = P00*r10 + P01*r11 + P02*r12;
    float w02 = P00*r20 + P01*r21 + P02*r22;
    float w11 = P10*r10 + P11*r11 + P12*r12;
    float w12 = P10*r20 + P11*r21 + P12*r22;
    float w22 = P20*r20 + P21*r21 + P22*r22;

    float g0 = fx / zc;
    float g2 = -fx * px / (zc * zc);
    float h1 = fy / zc;
    float h2 = -fy * py / (zc * zc);
    float a = g0*g0*w00 + 2.f*g0*g2*w02 + g2*g2*w22 + 0.3f;
    float b = g0*(w01*h1 + w02*h2) + g2*(w12*h1 + w22*h2);
    float c = h1*h1*w11 + 2.f*h1*h2*w12 + h2*h2*w22 + 0.3f;
    float det = a*c - b*b;
    float det_safe = (det > 0.f) ? det : 1.f;
    float conicA = c / det_safe;
    float conicB = -b / det_safe;
    float conicC = a / det_safe;

    float u = fx * px / zc + cx;
    float v = fy * py / zc + cy;

    // SH deg3
    float cpx = -(r00*t0 + r10*t1 + r20*t2);
    float cpy = -(r01*t0 + r11*t1 + r21*t2);
    float cpz = -(r02*t0 + r12*t1 + r22*t2);
    float vx = mx - cpx, vy = my - cpy, vz = mz - cpz;
    float vn = rsqrtf(vx*vx + vy*vy + vz*vz);
    float x = vx*vn, y = vy*vn, z = vz*vn;
    float xx = x*x, yy = y*y, zz = z*z;
    float bs[16];
    bs[0]  = 0.28209479177387814f;
    bs[1]  = -0.4886025119029199f * y;
    bs[2]  = 0.4886025119029199f * z;
    bs[3]  = -0.4886025119029199f * x;
    bs[4]  = 1.0925484305920792f * x * y;
    bs[5]  = -1.0925484305920792f * y * z;
    bs[6]  = 0.31539156525252005f * (2.f*zz - xx - yy);
    bs[7]  = -1.0925484305920792f * x * z;
    bs[8]  = 0.5462742152960396f * (xx - yy);
    bs[9]  = -0.5900435899266435f * y * (3.f*xx - yy);
    bs[10] = 2.890611442640554f * x * y * z;
    bs[11] = -0.4570457994644658f * y * (4.f*zz - xx - yy);
    bs[12] = 0.37317633259011546f * z * (2.f*zz - 3.f*xx - 3.f*yy);
    bs[13] = -0.4570457994644658f * x * (4.f*zz - xx - yy);
    bs[14] = 1.445305721320277f * z * (xx - yy);
    bs[15] = -0.5900435899266435f * x * (xx - 3.f*yy);

    float cr = bs[0]*fdc[3*i+0];
    float cg = bs[0]*fdc[3*i+1];
    float cb = bs[0]*fdc[3*i+2];
    #pragma unroll
    for (int k = 1; k < 16; ++k) {
        const float* f = frest + (i*15 + (k-1))*3;
        cr += bs[k]*f[0];
        cg += bs[k]*f[1];
        cb += bs[k]*f[2];
    }
    cr = fmaxf(cr + 0.5f, 0.f);
    cg = fmaxf(cg + 0.5f, 0.f);
    cb = fmaxf(cb + 0.5f, 0.f);

    // conservative alpha>=1/255 footprint (bbox); exact w.r.t. per-pixel test
    float tau = fmaxf(__logf(255.f * opsi), 0.f);
    float rx = 1.01f * sqrtf(2.f * tau * a) + 1.0f;
    float ry = 1.01f * sqrtf(2.f * tau * c) + 1.0f;

    if (lane == 0) {
        ((float4*)(ws + BBB_OFF))[r] = make_float4(u - rx, v - ry, u + rx, v + ry);
        ((float4*)(ws + BD0_OFF))[r] = make_float4(u, v, 0.5f*conicA, conicB);
        ((float4*)(ws + BD1_OFF))[r] = make_float4(0.5f*conicC, opsi, cr, cg);
        (ws + BD2_OFF)[r] = cb;
    }
}

// one 8x8 pixel tile per 64-thread block; batch-ballot cull over sorted list
__global__ __launch_bounds__(64) void composite_tile(
    const float* __restrict__ ws, const float* __restrict__ bg,
    float* __restrict__ out, int W, int H, int ntx)
{
    __shared__ float4 ds0[64], ds1[64];
    __shared__ float  ds2[64];
    const int M = *(const int*)(ws + WS_CNT_OFF);
    const float4* bbB = (const float4*)(ws + BBB_OFF);
    const float4* d0B = (const float4*)(ws + BD0_OFF);
    const float4* d1B = (const float4*)(ws + BD1_OFF);
    const float*  d2B = ws + BD2_OFF;

    int lane = threadIdx.x;
    int tx = blockIdx.x % ntx, ty = blockIdx.x / ntx;
    float tx0 = tx*TS + 0.5f, tx1 = tx*TS + (TS - 0.5f);
    float ty0 = ty*TS + 0.5f, ty1 = ty*TS + (TS - 0.5f);
    int px = tx*TS + (lane & (TS-1)), py = ty*TS + (lane >> 3);
    float gx = px + 0.5f, gy = py + 0.5f;

    float T = 1.f, cr = 0.f, cg = 0.f, cb = 0.f;

    float4 cbb = make_float4(1e30f, 1e30f, -1e30f, -1e30f);
    float4 c0 = make_float4(0,0,0,0), c1 = make_float4(0,0,0,0);
    float  c2 = 0.f;
    if (lane < M) { cbb = bbB[lane]; c0 = d0B[lane]; c1 = d1B[lane]; c2 = d2B[lane]; }

    for (int base = 0; base < M; base += 64) {
        // prefetch next batch while we work on this one
        int nj = base + 64 + lane;
        float4 nbb = make_float4(1e30f, 1e30f, -1e30f, -1e30f);
        float4 n0 = make_float4(0,0,0,0), n1 = make_float4(0,0,0,0);
        float  n2 = 0.f;
        if (nj < M) { nbb = bbB[nj]; n0 = d0B[nj]; n1 = d1B[nj]; n2 = d2B[nj]; }

        bool ov = (base + lane < M) &
                  (cbb.x <= tx1) & (cbb.z >= tx0) &
                  (cbb.y <= ty1) & (cbb.w >= ty0);
        unsigned long long m = __ballot(ov);
        if (m) {
            ds0[lane] = c0; ds1[lane] = c1; ds2[lane] = c2;
            while (m) {
                int j = (int)__builtin_ctzll(m);
                m &= m - 1;
                float4 q0 = ds0[j];       // u, v, A2, B
                float4 q1 = ds1[j];       // C2, op, r, g
                float bc = ds2[j];
                float dx = gx - q0.x, dy = gy - q0.y;
                float sg = fmaf(dx, fmaf(q0.z, dx, q0.w*dy), q1.x*(dy*dy));
                float e  = __expf(-sg);
                float al = fminf(q1.y * e, 0.999f);
                bool ok = (sg >= 0.f) & (al >= 0.00392156862745098f);
                al = ok ? al : 0.f;
                float w = T * al;
                cr = fmaf(w, q1.z, cr);
                cg = fmaf(w, q1.w, cg);
                cb = fmaf(w, bc, cb);
                T = fmaf(-al, T, T);
            }
        }
        cbb = nbb; c0 = n0; c1 = n1; c2 = n2;
    }

    if (px < W && py < H) {
        int p = py*W + px;
        out[3*p+0] = fmaf(T, bg[0], cr);
        out[3*p+1] = fmaf(T, bg[1], cg);
        out[3*p+2] = fmaf(T, bg[2], cb);
    }
}

extern "C" void kernel_launch(void* const* d_in, const int* in_sizes, int n_in,
                              void* d_out, int out_size, void* d_ws, size_t ws_size,
                              hipStream_t stream) {
    const float* means  = (const float*)d_in[0];
    const float* scales = (const float*)d_in[1];
    const float* quats  = (const float*)d_in[2];
    const float* fdc    = (const float*)d_in[3];
    const float* frest  = (const float*)d_in[4];
    const float* opac   = (const float*)d_in[5];
    const float* vm     = (const float*)d_in[6];
    const float* Km     = (const float*)d_in[7];
    const float* bg     = (const float*)d_in[8];

    int N  = in_sizes[0] / 3;     // 1024
    int HW = out_size / 3;        // H*W
    // recover W,H host-side (square in this problem; divisor fallback otherwise)
    int W = (int)(sqrtf((float)HW) + 0.5f);
    while (W > 1 && HW % W) --W;
    int H = HW / W;

    float* ws  = (float*)d_ws;
    float* out = (float*)d_out;

    prep_rank_kernel<<<(N + 3) / 4, 256, 0, stream>>>(means, scales, quats, fdc,
                                                      frest, opac, vm, Km, ws, N);

    int ntx = (W + TS - 1) / TS;
    int nty = (H + TS - 1) / TS;
    composite_tile<<<ntx * nty, 64, 0, stream>>>(ws, bg, out, W, H, ntx);
}